// Round 8
// baseline (215.740 us; speedup 1.0000x reference)
//
#include <hip/hip_runtime.h>

typedef unsigned short u16;
typedef unsigned int u32;

#define N_NODES 100000
#define N_EDGES 50000
#define C 128
#define G_GEMM 1563               // ceil(100000/64) 64-row GEMM blocks
#define NCNT (N_EDGES + N_NODES)  // 150000 combined key space (edges then nodes)
#define NBUCKC 1172               // ceil(150000 / 128) coarse buckets (key>>7)
#define BCHUNK 2048               // incidences per bucketize block

static __device__ __forceinline__ float bf2f(u16 h) {
    u32 u = ((u32)h) << 16;
    float f;
    __builtin_memcpy(&f, &u, 4);
    return f;
}

static __device__ __forceinline__ u16 f2bf(float f) {
    u32 u;
    __builtin_memcpy(&u, &f, 4);
    return (u16)((u + 0x7fffu + ((u >> 16) & 1u)) >> 16);  // RNE
}

typedef short s16x8 __attribute__((ext_vector_type(8)));
typedef float f32x4 __attribute__((ext_vector_type(4)));

// ---------------- W transpose -> bf16: Wt[oc][k] = bf16(W[k][oc]) ----------
__global__ void transpose_w(const float* __restrict__ W, u16* __restrict__ Wt) {
    int idx = blockIdx.x * 256 + threadIdx.x;  // 16384 total
    int k = idx >> 7, oc = idx & 127;
    Wt[oc * 128 + k] = f2bf(W[k * 128 + oc]);
}

// ---------------- GEMM: LDS-staged x tile (r8 MSHR theory) -----------------
// r7 counters: 41us at 1.25 TB/s, 50MB traffic (12us floor). Theory: the
// MFMA A-layout load (lane m -> row m, 512B stride) touches 32 distinct
// lines PER INSTRUCTION -> one load fills the CU's ~32 L1 miss slots ->
// ~2KB in flight/CU -> 1.4 TB/s cap == measured. Fix: stage the 64x128 f32
// tile via global_load_lds width-16 (thread t <- bytes t*16: contiguous
// 4KB bursts, no VGPR round-trip), then read A-fragments from LDS.
// xw[n][oc] = x[n][:] . W[:][oc], bf16 out. One wave per 16-row tile;
// A[m=lane&15][k=quad*8+j]; D col=lane&15, row=quad*4+reg (verified m89/m91).
__global__ __launch_bounds__(256) void gemm_k(
    const float* __restrict__ x, const u16* __restrict__ Wt,
    u16* __restrict__ xw) {
    __shared__ float xs[64 * C];  // 32 KB -> 5 blocks/CU
    int tid = threadIdx.x;
    int blk = blockIdx.x;
    int lane = tid & 63;
    int wave = tid >> 6;

    // stage: 8 rounds x (256 thr x 16 B) = 32 KB; LDS dest = wave-uniform
    // base + lane*16 (HW rule); global src per-lane, guarded for the tail
    // block (rows >= N_NODES redirect to x[0]; their tiles are skipped).
    size_t gbase = (size_t)blk * 64 * C;  // float index of tile origin
#pragma unroll
    for (int rnd = 0; rnd < 8; ++rnd) {
        int fl = rnd * 1024 + wave * 256 + lane * 4;   // float offset in tile
        int grow = blk * 64 + (fl >> 7);
        const float* src = (grow < N_NODES) ? (x + gbase + fl) : x;
        __builtin_amdgcn_global_load_lds(
            (const __attribute__((address_space(1))) void*)src,
            (__attribute__((address_space(3))) void*)(xs + rnd * 1024 + wave * 256),
            16, 0, 0);
    }
    __syncthreads();

    int tile = blk * 4 + wave;
    if (tile >= 6250) return;
    int m = lane & 15;
    int quad = lane >> 4;
    int row0 = tile * 16;

    const float* xr = xs + (wave * 16 + m) * C + quad * 8;
    f32x4 acc[8];
#pragma unroll
    for (int nt = 0; nt < 8; ++nt) acc[nt] = (f32x4){0.f, 0.f, 0.f, 0.f};

    union { uint4 u; s16x8 v; } a[4];
#pragma unroll
    for (int kk = 0; kk < 4; ++kk) {
        float4 v0 = *(const float4*)(xr + kk * 32);
        float4 v1 = *(const float4*)(xr + kk * 32 + 4);
        a[kk].u.x = (u32)f2bf(v0.x) | ((u32)f2bf(v0.y) << 16);
        a[kk].u.y = (u32)f2bf(v0.z) | ((u32)f2bf(v0.w) << 16);
        a[kk].u.z = (u32)f2bf(v1.x) | ((u32)f2bf(v1.y) << 16);
        a[kk].u.w = (u32)f2bf(v1.z) | ((u32)f2bf(v1.w) << 16);
    }

#pragma unroll
    for (int kk = 0; kk < 4; ++kk) {
        int kb = kk * 32 + quad * 8;
#pragma unroll
        for (int nt = 0; nt < 8; ++nt) {
            union { uint4 u; s16x8 v; } b;
            b.u = *(const uint4*)(Wt + (size_t)(nt * 16 + m) * C + kb);
            acc[nt] = __builtin_amdgcn_mfma_f32_16x16x32_bf16(a[kk].v, b.v, acc[nt], 0, 0, 0);
        }
    }

#pragma unroll
    for (int nt = 0; nt < 8; ++nt) {
#pragma unroll
        for (int r = 0; r < 4; ++r) {
            int row = row0 + quad * 4 + r;
            xw[(size_t)row * C + nt * 16 + m] = f2bf(acc[nt][r]);
        }
    }
}

// ---------------- P1a: per-(block,bucket) counts — ZERO global atomics -----
// Device-scope atomics run memory-side (~2.4e10/s chip-wide); build CSR with
// a deterministic count-matrix sort instead. LDS histogram only.
__global__ __launch_bounds__(256) void bucket_hist_k(
    const int* __restrict__ ni, const int* __restrict__ ei,
    u32* __restrict__ cntM, int nnz, int nb1) {
    __shared__ u32 h[NBUCKC];
    for (int b = threadIdx.x; b < NBUCKC; b += 256) h[b] = 0;
    __syncthreads();
    int i0 = blockIdx.x * BCHUNK;
    int iend = min(i0 + BCHUNK, nnz);
    for (int i = i0 + threadIdx.x; i < iend; i += 256) {
        int e = ei[i], n = ni[i];
        atomicAdd(&h[e >> 7], 1u);                 // LDS atomic (fast)
        atomicAdd(&h[(N_EDGES + n) >> 7], 1u);
    }
    __syncthreads();
    for (int b = threadIdx.x; b < NBUCKC; b += 256)
        cntM[(size_t)b * nb1 + blockIdx.x] = h[b];  // plain stores
}

// ---------------- scan A: generic exclusive scan ---------------------------
__global__ __launch_bounds__(256) void scan_a2(const u32* __restrict__ cnt,
                                               u32* __restrict__ off,
                                               u32* __restrict__ bsum, int N) {
    __shared__ u32 wsum[4];
    int tid = threadIdx.x;
    int base = blockIdx.x * 1024 + tid * 4;
    u32 v0 = 0, v1 = 0, v2 = 0, v3 = 0;
    if (base + 3 < N) {
        uint4 v = *(const uint4*)(cnt + base);
        v0 = v.x; v1 = v.y; v2 = v.z; v3 = v.w;
    } else {
        if (base + 0 < N) v0 = cnt[base + 0];
        if (base + 1 < N) v1 = cnt[base + 1];
        if (base + 2 < N) v2 = cnt[base + 2];
        if (base + 3 < N) v3 = cnt[base + 3];
    }
    u32 s = v0 + v1 + v2 + v3;
    int lane = tid & 63, wv = tid >> 6;
    u32 x = s;
    for (int d = 1; d < 64; d <<= 1) {
        u32 y = __shfl_up(x, (unsigned)d);
        if (lane >= d) x += y;
    }
    if (lane == 63) wsum[wv] = x;
    __syncthreads();
    u32 wo = 0;
    for (int w = 0; w < 4; ++w) wo += (w < wv) ? wsum[w] : 0u;
    u32 ex = wo + x - s;
    if (base + 0 < N) off[base + 0] = ex;
    if (base + 1 < N) off[base + 1] = ex + v0;
    if (base + 2 < N) off[base + 2] = ex + v0 + v1;
    if (base + 3 < N) off[base + 3] = ex + v0 + v1 + v2;
    if (tid == 255) bsum[blockIdx.x] = wo + x;  // block total
}

// ---------------- scan B: exclusive scan of up to 512 block sums ----------
__global__ __launch_bounds__(256) void scan_b2(u32* __restrict__ bsum, int nb) {
    __shared__ u32 wsum[4];
    int t = threadIdx.x;
    u32 v0 = (2 * t < nb) ? bsum[2 * t] : 0u;
    u32 v1 = (2 * t + 1 < nb) ? bsum[2 * t + 1] : 0u;
    u32 s = v0 + v1;
    int lane = t & 63, wv = t >> 6;
    u32 x = s;
    for (int d = 1; d < 64; d <<= 1) {
        u32 y = __shfl_up(x, (unsigned)d);
        if (lane >= d) x += y;
    }
    if (lane == 63) wsum[wv] = x;
    __syncthreads();
    u32 wo = 0;
    for (int w = 0; w < 4; ++w) wo += (w < wv) ? wsum[w] : 0u;
    u32 ex = wo + x - s;
    if (2 * t < nb) bsum[2 * t] = ex;
    if (2 * t + 1 < nb) bsum[2 * t + 1] = ex + v0;
}

// ---------------- P1b: place entries bucket-grouped (LDS cursors only) -----
// pos = offM[bucket][blk] (+bsum) + LDS cursor. Entries packed 4B:
// (key&127)<<17 | val  (val <= 99999 < 2^17).
__global__ __launch_bounds__(256) void bucket_place_k(
    const int* __restrict__ ni, const int* __restrict__ ei,
    const u32* __restrict__ offM, const u32* __restrict__ bsum,
    u32* __restrict__ stage, int nnz, int nb1) {
    __shared__ u32 cur[NBUCKC];
    for (int b = threadIdx.x; b < NBUCKC; b += 256) {
        size_t idx = (size_t)b * nb1 + blockIdx.x;
        cur[b] = offM[idx] + bsum[idx >> 10];
    }
    __syncthreads();
    int i0 = blockIdx.x * BCHUNK;
    int iend = min(i0 + BCHUNK, nnz);
    for (int i = i0 + threadIdx.x; i < iend; i += 256) {
        int e = ei[i], n = ni[i];
        u32 p1 = atomicAdd(&cur[e >> 7], 1u);
        stage[p1] = ((u32)(e & 127) << 17) | (u32)n;
        int k2 = N_EDGES + n;
        u32 p2 = atomicAdd(&cur[k2 >> 7], 1u);
        stage[p2] = ((u32)(k2 & 127) << 17) | (u32)e;
    }
}

// ---------------- P2: per-bucket fine counting-sort -> dense CSR + rowinfo --
// One block per bucket (~853 entries, 128 keys). rowinfo[key] = {GLOBAL
// start in combined csr, deg}. Edge keys sort before node keys, so
// csr[0..nnz) = edge lists, csr[nnz..2nnz) = node lists.
__global__ __launch_bounds__(256) void bucket_csr_k(
    const u32* __restrict__ offM, const u32* __restrict__ bsum,
    const u32* __restrict__ stage, u32* __restrict__ csr,
    uint2* __restrict__ rowinfo, int nnz, int nb1) {
    __shared__ u32 h[128];
    __shared__ u32 ks[128];
    int b = blockIdx.x;
    size_t i0 = (size_t)b * nb1;
    u32 gstart = offM[i0] + bsum[i0 >> 10];
    u32 gend;
    if (b + 1 < NBUCKC) {
        size_t i1 = (size_t)(b + 1) * nb1;
        gend = offM[i1] + bsum[i1 >> 10];
    } else {
        gend = (u32)(2 * nnz);
    }
    int size = (int)(gend - gstart);
    if (threadIdx.x < 128) h[threadIdx.x] = 0;
    __syncthreads();
    for (int i = threadIdx.x; i < size; i += 256)
        atomicAdd(&h[stage[gstart + i] >> 17], 1u);
    __syncthreads();
    if (threadIdx.x < 64) {
        int l = threadIdx.x;
        u32 s0 = h[2 * l], s1 = h[2 * l + 1];
        u32 ps = s0 + s1;
        u32 x = ps;
        for (int d = 1; d < 64; d <<= 1) {
            u32 y = __shfl_up(x, (unsigned)d);
            if (l >= d) x += y;
        }
        u32 ex = x - ps;  // exclusive pair prefix within bucket
        ks[2 * l] = ex;
        ks[2 * l + 1] = ex + s0;
        int gk = b * 128 + 2 * l;
        if (gk < NCNT) rowinfo[gk] = make_uint2(gstart + ex, s0);
        if (gk + 1 < NCNT) rowinfo[gk + 1] = make_uint2(gstart + ex + s0, s1);
    }
    __syncthreads();
    for (int i = threadIdx.x; i < size; i += 256) {
        u32 en = stage[gstart + i];
        u32 kl = en >> 17;
        u32 p = atomicAdd(&ks[kl], 1u);
        csr[gstart + p] = en & 0x1FFFFu;
    }
}

// ---------------- 8-wide branchless gather body (r6, unchanged) ------------
#define GATHER8(SRC)                                                          \
    for (u32 base = 0; base < deg; base += 64) {                              \
        int m = (int)min(64u, deg - base);                                    \
        int myidx = (lane < m) ? (int)csr[start + base + lane] : 0;           \
        for (int t = 0; t < m; t += 8) {                                      \
            int i1 = min(t + 1, m - 1), i2 = min(t + 2, m - 1);               \
            int i3 = min(t + 3, m - 1), i4 = min(t + 4, m - 1);               \
            int i5 = min(t + 5, m - 1), i6 = min(t + 6, m - 1);               \
            int i7 = min(t + 7, m - 1);                                       \
            int r0 = __shfl(myidx, t),  r1 = __shfl(myidx, i1);               \
            int r2 = __shfl(myidx, i2), r3 = __shfl(myidx, i3);               \
            int r4 = __shfl(myidx, i4), r5 = __shfl(myidx, i5);               \
            int r6 = __shfl(myidx, i6), r7 = __shfl(myidx, i7);               \
            u32 u0 = ((const u32*)(SRC + (size_t)r0 * C))[lane];              \
            u32 u1 = ((const u32*)(SRC + (size_t)r1 * C))[lane];              \
            u32 u2 = ((const u32*)(SRC + (size_t)r2 * C))[lane];              \
            u32 u3 = ((const u32*)(SRC + (size_t)r3 * C))[lane];              \
            u32 u4 = ((const u32*)(SRC + (size_t)r4 * C))[lane];              \
            u32 u5 = ((const u32*)(SRC + (size_t)r5 * C))[lane];              \
            u32 u6 = ((const u32*)(SRC + (size_t)r6 * C))[lane];              \
            u32 u7 = ((const u32*)(SRC + (size_t)r7 * C))[lane];              \
            float k1 = (t + 1 < m) ? 1.f : 0.f, k2 = (t + 2 < m) ? 1.f : 0.f; \
            float k3 = (t + 3 < m) ? 1.f : 0.f, k4 = (t + 4 < m) ? 1.f : 0.f; \
            float k5 = (t + 5 < m) ? 1.f : 0.f, k6 = (t + 6 < m) ? 1.f : 0.f; \
            float k7 = (t + 7 < m) ? 1.f : 0.f;                               \
            ax += bf2f((u16)(u0 & 0xffffu)) + k1 * bf2f((u16)(u1 & 0xffffu))  \
                + k2 * bf2f((u16)(u2 & 0xffffu)) + k3 * bf2f((u16)(u3 & 0xffffu)) \
                + k4 * bf2f((u16)(u4 & 0xffffu)) + k5 * bf2f((u16)(u5 & 0xffffu)) \
                + k6 * bf2f((u16)(u6 & 0xffffu)) + k7 * bf2f((u16)(u7 & 0xffffu)); \
            ay += bf2f((u16)(u0 >> 16)) + k1 * bf2f((u16)(u1 >> 16))          \
                + k2 * bf2f((u16)(u2 >> 16)) + k3 * bf2f((u16)(u3 >> 16))     \
                + k4 * bf2f((u16)(u4 >> 16)) + k5 * bf2f((u16)(u5 >> 16))     \
                + k6 * bf2f((u16)(u6 >> 16)) + k7 * bf2f((u16)(u7 >> 16));    \
        }                                                                     \
    }

// ---------------- edge gather over CSR: 1 edge per wave -------------------
__global__ __launch_bounds__(256) void edge_gather_k(const u16* __restrict__ xw,
                                                     const uint2* __restrict__ rowinfo,
                                                     const u32* __restrict__ csrC,
                                                     u16* __restrict__ ef) {
    int e = blockIdx.x * 4 + (threadIdx.x >> 6);
    if (e >= N_EDGES) return;
    int lane = threadIdx.x & 63;
    uint2 ri = rowinfo[e];
    u32 deg = ri.y;
    u32 start = ri.x;  // absolute position in combined csr
    const u32* csr = csrC;
    float ax = 0.f, ay = 0.f;
    GATHER8(xw)
    float sc = deg ? 1.f / (float)deg : 0.f;
    ((u32*)(ef + (size_t)e * C))[lane] =
        (u32)f2bf(ax * sc) | ((u32)f2bf(ay * sc) << 16);
}

// ---------------- node gather over CSR: 1 node per wave -------------------
__global__ __launch_bounds__(256) void node_gather_k(const u16* __restrict__ ef,
                                                     const uint2* __restrict__ rowinfo,
                                                     const u32* __restrict__ csrC,
                                                     const float* __restrict__ bias,
                                                     float* __restrict__ out) {
    int v = blockIdx.x * 4 + (threadIdx.x >> 6);
    if (v >= N_NODES) return;
    int lane = threadIdx.x & 63;
    uint2 ri = rowinfo[N_EDGES + v];
    u32 deg = ri.y;
    u32 start = ri.x;  // absolute position in combined csr
    const u32* csr = csrC;
    float ax = 0.f, ay = 0.f;
    GATHER8(ef)
    float b0 = bias[2 * lane], b1 = bias[2 * lane + 1];
    float sc = deg ? 1.f / (float)deg : 0.f;
    float2 r;
    r.x = ax * sc + b0;
    r.y = ay * sc + b1;
    ((float2*)(out + (size_t)v * C))[lane] = r;
}

extern "C" void kernel_launch(void* const* d_in, const int* in_sizes, int n_in,
                              void* d_out, int out_size, void* d_ws, size_t ws_size,
                              hipStream_t stream) {
    const float* x = (const float*)d_in[0];     // [N_NODES,128] f32
    const int* node_idx = (const int*)d_in[1];  // [2, NNZ] row-major int32
    const int nnz = in_sizes[1] / 2;
    const int* edge_idx = node_idx + nnz;
    const float* W = (const float*)d_in[2];     // [128,128] f32
    const float* bias = (const float*)d_in[3];  // [128] f32
    float* out = (float*)d_out;                 // [N_NODES,128] f32

    int nb1 = (nnz + BCHUNK - 1) / BCHUNK;      // 245 bucketize blocks
    int scanN = NBUCKC * nb1;                   // 287140 count-matrix entries
    int scanBlocks = (scanN + 1023) / 1024;     // 281 (<= 512 for scan_b2)

    // workspace layout (~20.3 MB), all 16B-aligned:
    u16* Wt = (u16*)d_ws;                           // 32 KB
    u16* ef = Wt + 16384;                           // 12.8 MB
    u32* cntM = (u32*)(ef + (size_t)N_EDGES * C);   // scanN u32 (1.15 MB)
    u32* offM = cntM + scanN;                       // scanN u32 (1.15 MB)
    u32* bsum2 = offM + scanN;                      // 512 u32
    uint2* rowinfo = (uint2*)(bsum2 + 512);         // 150000 uint2 (1.2 MB)
    u32* csrC = (u32*)(rowinfo + NCNT);             // 2*nnz u32 (4 MB)

    // d_out (51.2 MB f32) doubles as scratch:
    //   [0, 25.6 MB):    xw bf16        — consumed by edge_gather
    //   [25.6, 29.6 MB): stage (packed) — consumed by bucket_csr_k
    //   (gemm's guarded tail rows may scribble on stage[0..8KB); harmless:
    //    bucket_place_k writes stage AFTER gemm completes.)
    // node_gather then overwrites the whole buffer with the f32 output.
    u16* xw = (u16*)d_out;
    u32* stage = (u32*)((char*)d_out + (size_t)N_NODES * C * 2);

    transpose_w<<<64, 256, 0, stream>>>(W, Wt);
    gemm_k<<<G_GEMM, 256, 0, stream>>>(x, Wt, xw);
    bucket_hist_k<<<nb1, 256, 0, stream>>>(node_idx, edge_idx, cntM, nnz, nb1);
    scan_a2<<<scanBlocks, 256, 0, stream>>>(cntM, offM, bsum2, scanN);
    scan_b2<<<1, 256, 0, stream>>>(bsum2, scanBlocks);
    bucket_place_k<<<nb1, 256, 0, stream>>>(node_idx, edge_idx, offM, bsum2,
                                            stage, nnz, nb1);
    bucket_csr_k<<<NBUCKC, 256, 0, stream>>>(offM, bsum2, stage, csrC, rowinfo,
                                             nnz, nb1);
    // 1 edge/node per wave, 4 waves per block
    edge_gather_k<<<(N_EDGES + 3) / 4, 256, 0, stream>>>(xw, rowinfo, csrC, ef);
    node_gather_k<<<(N_NODES + 3) / 4, 256, 0, stream>>>(ef, rowinfo, csrC, bias, out);
}